// Round 9
// baseline (6836.276 us; speedup 1.0000x reference)
//
#include <hip/hip_runtime.h>

#define BB 256
#define TT 2048
#define HH 128
#define G4 512     // 4*H gate rows
#define INW 4
#define OUTW 4
#define TC 56      // time-chunk; LDS-resident (2048 = 36*56 + 32, both even)
#define NT 1024
#define HW 64      // half-row width

typedef _Float16 f16x2 __attribute__((ext_vector_type(2)));

__device__ __forceinline__ float sigm(float x) {
    return __fdividef(1.f, 1.f + __expf(-x));
}
__device__ __forceinline__ float tanh_(float x) {
    return __fdividef(2.f, 1.f + __expf(-2.f * x)) - 1.f;
}

// R8 lesson: v_dot2_f32_f16 has coarser internal rounding than fp32 FMA;
// through a 2048-step recurrence the error grew 17x (8.3e-3 > 2.03e-3 thr).
// Use v_fma_mix_f32 instead: fp32 FMA with f16 operands picked from register
// halves (op_sel) — numerics identical to R7's cvt+fma (passed at 4.9e-4),
// but 1 instruction per product: 64 MACs/step vs R7's measured 175 VALU/step
// (compiler kept 128 converts in-loop).
// MIX2: acc += f16lo(W)*f16lo(H) then += f16hi(W)*f16hi(H), both fp32 FMAs.
#define MIX2(acc, W, HWD) do {                                                 \
    asm("v_fma_mix_f32 %0, %1, %2, %0 op_sel_hi:[1,1,0]"                       \
        : "+v"(acc) : "v"(W), "v"(HWD));                                       \
    asm("v_fma_mix_f32 %0, %1, %2, %0 op_sel:[1,1,0] op_sel_hi:[1,1,0]"        \
        : "+v"(acc) : "v"(W), "v"(HWD));                                       \
} while (0)

#define DOTK(k, W0, W1, W2, W3) do { const uint4 hw_ = hp_[k];                 \
    MIX2(a0, W0, hw_.x); MIX2(a1, W1, hw_.y);                                  \
    MIX2(a2, W2, hw_.z); MIX2(a3, W3, hw_.w); } while (0)

#define DOTH(HB) do { const uint4* hp_ = (const uint4*)(HB);                   \
    DOTK(0,  w0,  w1,  w2,  w3);  DOTK(1,  w4,  w5,  w6,  w7);                 \
    DOTK(2,  w8,  w9,  w10, w11); DOTK(3,  w12, w13, w14, w15);                \
    DOTK(4,  w16, w17, w18, w19); DOTK(5,  w20, w21, w22, w23);                \
    DOTK(6,  w24, w25, w26, w27); DOTK(7,  w28, w29, w30, w31); } while (0)

#define LW2(m, WA, WB) { const float4 t_ = wb_[m];                             \
    WA = (f16x2){(_Float16)t_.x, (_Float16)t_.y};                              \
    WB = (f16x2){(_Float16)t_.z, (_Float16)t_.w}; }

#define LOADW(M) do {                                                          \
    const float4* wb_ = (const float4*)((M) + (size_t)r * HH + hoff);          \
    LW2(0,  w0,  w1);  LW2(1,  w2,  w3);  LW2(2,  w4,  w5);                    \
    LW2(3,  w6,  w7);  LW2(4,  w8,  w9);  LW2(5,  w10, w11);                   \
    LW2(6,  w12, w13); LW2(7,  w14, w15); LW2(8,  w16, w17);                   \
    LW2(9,  w18, w19); LW2(10, w20, w21); LW2(11, w22, w23);                   \
    LW2(12, w24, w25); LW2(13, w26, w27); LW2(14, w28, w29);                   \
    LW2(15, w30, w31);                                                         \
} while (0)

extern "C" __global__ void
__attribute__((amdgpu_flat_work_group_size(NT, NT)))
__attribute__((amdgpu_waves_per_eu(4, 4)))
lstm2_fused(const float* __restrict__ x,
            const float* __restrict__ Wih0, const float* __restrict__ Whh0,
            const float* __restrict__ bih0, const float* __restrict__ bhh0,
            const float* __restrict__ Wih1, const float* __restrict__ Whh1,
            const float* __restrict__ bih1, const float* __restrict__ bhh1,
            const float* __restrict__ Wlin, const float* __restrict__ blin,
            float* __restrict__ out)
{
    // STATIC LDS: 130,688 B of 160 KB
    __shared__ _Float16 h1h[(TC + 1) * HH];  // h1 ring (f16); row i = h1 at local step i-1
    __shared__ float    xg1c[TC * G4];       // layer-1 input gates (fp32)
    __shared__ _Float16 h2h[2 * HH];         // h2 double buffer (f16), parity = t&1
    __shared__ float    xc[TC * INW];        // x chunk

    const int i     = threadIdx.x;
    const int half  = i & 1;                 // half of the row
    const int g     = (i >> 1) & 3;          // gate (0=i,1=f,2=g,3=o)
    const int u     = i >> 3;                // unit 0..127
    const int r     = (g << 7) | u;          // gate row 0..511
    const int hoff  = half * HW;
    const int gbase = i & 56;                // lane base of my unit's 8-lane group
    const int b     = blockIdx.x;

    float bias0 = 0.f, bias1 = 0.f, wx0 = 0.f, wx1 = 0.f, wx2 = 0.f, wx3 = 0.f;
    if (!half) {
        bias0 = bih0[r] + bhh0[r];
        bias1 = bih1[r] + bhh1[r];
        wx0 = Wih0[r*INW+0]; wx1 = Wih0[r*INW+1];
        wx2 = Wih0[r*INW+2]; wx3 = Wih0[r*INW+3];
    }

    float wlA = 0.f, wlB = 0.f, bl = 0.f;    // projection (threads 0..255)
    if (i < OUTW * 64) {
        const int o = i >> 6, l = i & 63;
        wlA = Wlin[o*HH + l];
        wlB = Wlin[o*HH + 64 + l];
        bl  = blin[o];
    }

    float c1 = 0.f, c2 = 0.f;                // cell state, replicated per 8-lane unit group
    if (i < HH) { h1h[i] = (_Float16)0.f; h2h[i] = (_Float16)0.f; }

    f16x2 w0,  w1,  w2,  w3,  w4,  w5,  w6,  w7,
          w8,  w9,  w10, w11, w12, w13, w14, w15,
          w16, w17, w18, w19, w20, w21, w22, w23,
          w24, w25, w26, w27, w28, w29, w30, w31;

    const float* xb   = x   + (size_t)b * TT * INW;
    float*       vout = out + (size_t)b * TT * OUTW;
    float*       zout = out + (size_t)BB * TT * OUTW + (size_t)b * HH;

    for (int t0 = 0; t0 < TT; t0 += TC) {
        const int tc = (TT - t0 < TC) ? (TT - t0) : TC;

        if (t0 > 0 && i < HH) h1h[i] = h1h[TC * HH + i];   // carry h1 ring
        for (int j = i; j < tc * INW; j += NT) xc[j] = xb[t0 * INW + j];

        // ================= Phase A: layer-0 recurrence =================
        LOADW(Whh0);
        __syncthreads();

        for (int t = 0; t < tc; ++t) {
            float a0 = 0.f, a1 = 0.f, a2 = 0.f, a3 = 0.f;
            if (!half) {
                const float4 xv = *(const float4*)(xc + t * INW);
                a0 = bias0 + xv.x*wx0 + xv.y*wx1 + xv.z*wx2 + xv.w*wx3;
            }
            DOTH(h1h + t * HH + hoff);
            float p = (a0 + a1) + (a2 + a3);
            p += __shfl_xor(p, 1);                         // combine halves
            const float act = (g == 2) ? tanh_(p) : sigm(p);
            const float A0 = __shfl(act, gbase);           // i-gate
            const float A1 = __shfl(act, gbase | 2);       // f
            const float A2 = __shfl(act, gbase | 4);       // g
            const float A3 = __shfl(act, gbase | 6);       // o
            c1 = A1 * c1 + A0 * A2;
            const float hn = A3 * tanh_(c1);
            if ((i & 7) == 0) h1h[(t + 1) * HH + u] = (_Float16)hn;
            __syncthreads();
        }

        // ================= Phase B: xg1 = h1 @ Wih1^T + biases =========
        LOADW(Wih1);
        for (int t = 0; t < tc; ++t) {                     // no per-t dependency
            float a0 = half ? 0.f : bias1, a1 = 0.f, a2 = 0.f, a3 = 0.f;
            DOTH(h1h + (t + 1) * HH + hoff);
            float p = (a0 + a1) + (a2 + a3);
            p += __shfl_xor(p, 1);
            if (!half) xg1c[t * G4 + r] = p;
        }
        __syncthreads();

        // ====== Phase C: layer-1 recurrence + output projection ========
        LOADW(Whh1);
        for (int t = 0; t < tc; ++t) {
            const int rb = (t & 1) * HH;                   // read buffer
            const int wb = rb ^ HH;                        // write buffer
            float a0 = half ? 0.f : xg1c[t * G4 + r];
            float a1 = 0.f, a2 = 0.f, a3 = 0.f;
            DOTH(h2h + rb + hoff);
            float p = (a0 + a1) + (a2 + a3);
            p += __shfl_xor(p, 1);
            const float act = (g == 2) ? tanh_(p) : sigm(p);
            const float A0 = __shfl(act, gbase);
            const float A1 = __shfl(act, gbase | 2);
            const float A2 = __shfl(act, gbase | 4);
            const float A3 = __shfl(act, gbase | 6);
            c2 = A1 * c2 + A0 * A2;
            const float hn = A3 * tanh_(c2);
            if ((i & 7) == 0) {
                h2h[wb + u] = (_Float16)hn;
                if (t0 + t == TT - 1) zout[u] = hn;        // z = zs[:,-1], fp32-exact
            }
            __syncthreads();
            if (i < OUTW * 64) {                           // projection from fresh h2
                const int l = i & 63;
                float p2 = (float)h2h[wb + l] * wlA + (float)h2h[wb + 64 + l] * wlB;
                p2 += __shfl_xor(p2, 32);
                p2 += __shfl_xor(p2, 16);
                p2 += __shfl_xor(p2, 8);
                p2 += __shfl_xor(p2, 4);
                p2 += __shfl_xor(p2, 2);
                p2 += __shfl_xor(p2, 1);
                if (l == 0) vout[(size_t)(t0 + t) * OUTW + (i >> 6)] = p2 + bl;
            }
        }
        // next chunk's staging writes (h1h row0, xc) are disjoint from the
        // projection reads above; the chunk-top __syncthreads gates phase A.
    }
}

extern "C" void kernel_launch(void* const* d_in, const int* in_sizes, int n_in,
                              void* d_out, int out_size, void* d_ws, size_t ws_size,
                              hipStream_t stream) {
    const float* x    = (const float*)d_in[0];
    const float* Wih0 = (const float*)d_in[1];
    const float* Whh0 = (const float*)d_in[2];
    const float* bih0 = (const float*)d_in[3];
    const float* bhh0 = (const float*)d_in[4];
    const float* Wih1 = (const float*)d_in[5];
    const float* Whh1 = (const float*)d_in[6];
    const float* bih1 = (const float*)d_in[7];
    const float* bhh1 = (const float*)d_in[8];
    const float* Wlin = (const float*)d_in[9];
    const float* blin = (const float*)d_in[10];
    float* out = (float*)d_out;

    lstm2_fused<<<dim3(BB), dim3(NT), 0, stream>>>(
        x, Wih0, Whh0, bih0, bhh0, Wih1, Whh1, bih1, bhh1, Wlin, blin, out);
}

// Round 11
// 6720.722 us; speedup vs baseline: 1.0172x; 1.0172x over previous
//
#include <hip/hip_runtime.h>

#define BB 256
#define TT 2048
#define HH 128
#define G4 512     // 4*H gate rows
#define INW 4
#define OUTW 4
#define TC 56      // time-chunk; 2048 = 36*56 + 32, both even
#define NT 1024

typedef _Float16 f16x8 __attribute__((ext_vector_type(8)));
typedef float    f32x4 __attribute__((ext_vector_type(4)));

#define MFMA(A,B,C) __builtin_amdgcn_mfma_f32_16x16x32_f16((A),(B),(C),0,0,0)

__device__ __forceinline__ float sigm(float x)  { return __fdividef(1.f, 1.f + __expf(-x)); }
__device__ __forceinline__ float tanh_(float x) { return __fdividef(2.f, 1.f + __expf(-2.f*x)) - 1.f; }

// R10 post-mortem: absmax 3.7e-2 was NOT a fragment-layout error (that would be
// O(1) garbage) — it was b1c[] filled ROW-indexed but read CG-indexed in phase
// B (bias permutation, ~0.13 typical error -> ~4e-2 in v). Fix: read b1c via
// the W-row (grow0/grow1). MFMA layouts (verified by the near-pass):
//   A: lane l holds A[row=l&15][k=(l>>4)*8+e]
//   B: lane l holds B[k=(l>>4)*8+e][col=l&15]
//   C: lane l holds C[row=(l>>4)*4+reg][col=l&15]  (guide m89/m121-128)
// Gate-column map: cg = w*32 + tile*16 + col; unit = cg>>2, gate = cg&3
//   -> W row = gate*128 + unit. f16 weights/h, fp32 MFMA accumulate.

// Load one W B-fragment: 8 consecutive fp32 -> f16x8
#define LDFRAG(dst, grow_, kf) do {                                            \
    const float* p_ = Mp_ + (size_t)(grow_)*HH + (kf)*32 + (kq<<3);            \
    const float4 lo_ = *(const float4*)p_;                                     \
    const float4 hi_ = *(const float4*)(p_ + 4);                               \
    dst = (f16x8){(_Float16)lo_.x,(_Float16)lo_.y,(_Float16)lo_.z,             \
                  (_Float16)lo_.w,(_Float16)hi_.x,(_Float16)hi_.y,             \
                  (_Float16)hi_.z,(_Float16)hi_.w}; } while (0)

#define LOADW(M) do { const float* Mp_ = (M);                                  \
    LDFRAG(b00, grow0, 0); LDFRAG(b01, grow0, 1);                              \
    LDFRAG(b02, grow0, 2); LDFRAG(b03, grow0, 3);                              \
    LDFRAG(b10, grow1, 0); LDFRAG(b11, grow1, 1);                              \
    LDFRAG(b12, grow1, 2); LDFRAG(b13, grow1, 3); } while (0)

// one K-frag of a recurrence step: masked h load (4 lanes) + 2 MFMAs
#define STEPK(kf, HB) do {                                                     \
    f16x8 ha_ = {0,0,0,0,0,0,0,0};                                             \
    if (colz) ha_ = *(const f16x8*)((HB) + (kf)*32 + (kq<<3));                 \
    ac0 = MFMA(ha_, b0##kf, ac0); ac1 = MFMA(ha_, b1##kf, ac1); } while (0)

// one K-frag of the bulk xg1 GEMM: full-lane h load (A rows = 16 time steps)
#define STEPKB(kf) do {                                                        \
    const f16x8 ha_ = *(const f16x8*)(hbB + (kf)*32 + (kq<<3));                \
    ac0 = MFMA(ha_, b0##kf, ac0); ac1 = MFMA(ha_, b1##kf, ac1); } while (0)

extern "C" __global__ void
__attribute__((amdgpu_flat_work_group_size(NT, NT)))
lstm2_fused(const float* __restrict__ x,
            const float* __restrict__ Wih0, const float* __restrict__ Whh0,
            const float* __restrict__ bih0, const float* __restrict__ bhh0,
            const float* __restrict__ Wih1, const float* __restrict__ Whh1,
            const float* __restrict__ bih1, const float* __restrict__ bhh1,
            const float* __restrict__ Wlin, const float* __restrict__ blin,
            float* __restrict__ out)
{
    // STATIC LDS ~136.6 KB (h1h oversized to 65 rows so phase-B's padded
    // 16-row A-tiles read in-bounds garbage, guarded on write)
    __shared__ __align__(16) _Float16 h1h[(TC + 9) * HH];  // h1 ring, rows 0..64
    __shared__ float buf[TC * G4];          // xg0 (phase A) then xg1 (phase C)
    __shared__ __align__(16) _Float16 h2h[2 * HH];         // h2 dbuf, parity t&1
    __shared__ float xc[TC * INW];          // x chunk
    __shared__ float b1c[G4];               // bias1 by W-ROW index
    __shared__ float wlc[OUTW * HH];        // Wlin
    __shared__ float blc[OUTW];

    const int i    = threadIdx.x;
    const int w    = i >> 6;               // wave 0..15
    const int lane = i & 63;
    const int col  = lane & 15;
    const int kq   = lane >> 4;            // K-quarter 0..3
    const bool colz = (col == 0);
    const int b    = blockIdx.x;

    const int cg0   = (w << 5) | col;      // tile0 gate-col (0..511)
    const int cg1   = cg0 + 16;            // tile1 gate-col
    const int grow0 = ((cg0 & 3) << 7) | (cg0 >> 2);   // W row of cg0
    const int grow1 = ((cg1 & 3) << 7) | (cg1 >> 2);
    // owner-lane (0..15) decode
    const int gate = col & 3;
    const int gb   = col & 12;             // 4-lane group base
    const int uA   = cg0 >> 2;             // unit of tile0 col
    const int uB   = cg1 >> 2;             // unit of tile1 col

    if (i < G4)       b1c[i] = bih1[i] + bhh1[i];   // ROW-indexed
    if (i < OUTW*HH)  wlc[i] = Wlin[i];
    if (i < OUTW)     blc[i] = blin[i];
    if (i < HH) { h1h[i] = (_Float16)0.f; h2h[i] = (_Float16)0.f; }

    float c1A = 0.f, c1B = 0.f, c2A = 0.f, c2B = 0.f;
    f16x8 b00, b01, b02, b03, b10, b11, b12, b13;

    const float* xb   = x   + (size_t)b * TT * INW;
    float*       vout = out + (size_t)b * TT * OUTW;
    float*       zout = out + (size_t)BB * TT * OUTW + (size_t)b * HH;

    for (int t0 = 0; t0 < TT; t0 += TC) {
        const int tc = (TT - t0 < TC) ? (TT - t0) : TC;

        if (t0 > 0 && i < HH) h1h[i] = h1h[TC * HH + i];   // carry ring
        for (int j = i; j < tc * INW; j += NT) xc[j] = xb[t0 * INW + j];
        __syncthreads();

        // -------- xg0 bulk: buf[t][cg] = bias0 + Wih0 . x_t (L2-hot loads)
        for (int idx = i; idx < tc * G4; idx += NT) {
            const int t  = idx >> 9, cg = idx & 511;
            const int row = ((cg & 3) << 7) | (cg >> 2);
            const float4 wv = *(const float4*)(Wih0 + (size_t)row * INW);
            const float4 xv = *(const float4*)(xc + t * INW);
            buf[idx] = bih0[row] + bhh0[row]
                     + wv.x*xv.x + wv.y*xv.y + wv.z*xv.z + wv.w*xv.w;
        }
        LOADW(Whh0);
        __syncthreads();

        // ================= Phase A: layer-0 recurrence =================
        for (int t = 0; t < tc; ++t) {
            f32x4 ac0 = {0.f,0.f,0.f,0.f}, ac1 = {0.f,0.f,0.f,0.f};
            const _Float16* hb = h1h + t * HH;
            STEPK(0, hb); STEPK(1, hb); STEPK(2, hb); STEPK(3, hb);
            if (lane < 16) {
                const float gAv = ac0[0] + buf[t * G4 + cg0];
                const float gBv = ac1[0] + buf[t * G4 + cg1];
                const float aA = (gate == 2) ? tanh_(gAv) : sigm(gAv);
                const float aB = (gate == 2) ? tanh_(gBv) : sigm(gBv);
                const float A0 = __shfl(aA, gb),     A1 = __shfl(aA, gb | 1);
                const float A2 = __shfl(aA, gb | 2), A3 = __shfl(aA, gb | 3);
                const float B0 = __shfl(aB, gb),     B1 = __shfl(aB, gb | 1);
                const float B2 = __shfl(aB, gb | 2), B3 = __shfl(aB, gb | 3);
                c1A = A1 * c1A + A0 * A2;
                c1B = B1 * c1B + B0 * B2;
                if (gate == 0) {
                    h1h[(t + 1) * HH + uA] = (_Float16)(A3 * tanh_(c1A));
                    h1h[(t + 1) * HH + uB] = (_Float16)(B3 * tanh_(c1B));
                }
            }
            __syncthreads();
        }

        // ===== Phase B: xg1 = Wih1 @ h1 + b1 (bulk MFMA, 16 t's per tile)
        LOADW(Wih1);
        const int ntb = (tc + 15) >> 4;
        for (int tb = 0; tb < ntb; ++tb) {
            f32x4 ac0 = {0.f,0.f,0.f,0.f}, ac1 = {0.f,0.f,0.f,0.f};
            const _Float16* hbB = h1h + (tb * 16 + col + 1) * HH;
            STEPKB(0); STEPKB(1); STEPKB(2); STEPKB(3);
            const float bA = b1c[grow0], bBv = b1c[grow1];   // FIX: row-indexed
            #pragma unroll
            for (int e = 0; e < 4; ++e) {
                const int tl = tb * 16 + kq * 4 + e;   // C row = time step
                if (tl < tc) {
                    buf[tl * G4 + cg0] = ac0[e] + bA;
                    buf[tl * G4 + cg1] = ac1[e] + bBv;
                }
            }
        }
        __syncthreads();

        // ====== Phase C: layer-1 recurrence + output projection ========
        LOADW(Whh1);
        for (int t = 0; t < tc; ++t) {
            const int rb = (t & 1) * HH, wb = rb ^ HH;
            f32x4 ac0 = {0.f,0.f,0.f,0.f}, ac1 = {0.f,0.f,0.f,0.f};
            const _Float16* hb = h2h + rb;
            STEPK(0, hb); STEPK(1, hb); STEPK(2, hb); STEPK(3, hb);
            if (lane < 16) {
                const float gAv = ac0[0] + buf[t * G4 + cg0];
                const float gBv = ac1[0] + buf[t * G4 + cg1];
                const float aA = (gate == 2) ? tanh_(gAv) : sigm(gAv);
                const float aB = (gate == 2) ? tanh_(gBv) : sigm(gBv);
                const float A0 = __shfl(aA, gb),     A1 = __shfl(aA, gb | 1);
                const float A2 = __shfl(aA, gb | 2), A3 = __shfl(aA, gb | 3);
                const float B0 = __shfl(aB, gb),     B1 = __shfl(aB, gb | 1);
                const float B2 = __shfl(aB, gb | 2), B3 = __shfl(aB, gb | 3);
                c2A = A1 * c2A + A0 * A2;
                c2B = B1 * c2B + B0 * B2;
                if (gate == 0) {
                    const float hA = A3 * tanh_(c2A);
                    const float hB = B3 * tanh_(c2B);
                    h2h[wb + uA] = (_Float16)hA;
                    h2h[wb + uB] = (_Float16)hB;
                    if (t0 + t == TT - 1) { zout[uA] = hA; zout[uB] = hB; }
                }
            }
            __syncthreads();
            if (i < 256) {                               // v[b,t,:] projection
                const int o = i >> 6, l = i & 63;
                float p2 = (float)h2h[wb + l]      * wlc[o*HH + l]
                         + (float)h2h[wb + 64 + l] * wlc[o*HH + 64 + l];
                p2 += __shfl_xor(p2, 32);
                p2 += __shfl_xor(p2, 16);
                p2 += __shfl_xor(p2, 8);
                p2 += __shfl_xor(p2, 4);
                p2 += __shfl_xor(p2, 2);
                p2 += __shfl_xor(p2, 1);
                if (l == 0) vout[(size_t)(t0 + t) * OUTW + o] = p2 + blc[o];
            }
        }
        // chunk-top __syncthreads (after carry/xc staging) gates the next
        // chunk's buf overwrite against this chunk's stragglers.
    }
}

extern "C" void kernel_launch(void* const* d_in, const int* in_sizes, int n_in,
                              void* d_out, int out_size, void* d_ws, size_t ws_size,
                              hipStream_t stream) {
    const float* x    = (const float*)d_in[0];
    const float* Wih0 = (const float*)d_in[1];
    const float* Whh0 = (const float*)d_in[2];
    const float* bih0 = (const float*)d_in[3];
    const float* bhh0 = (const float*)d_in[4];
    const float* Wih1 = (const float*)d_in[5];
    const float* Whh1 = (const float*)d_in[6];
    const float* bih1 = (const float*)d_in[7];
    const float* bhh1 = (const float*)d_in[8];
    const float* Wlin = (const float*)d_in[9];
    const float* blin = (const float*)d_in[10];
    float* out = (float*)d_out;

    lstm2_fused<<<dim3(BB), dim3(NT), 0, stream>>>(
        x, Wih0, Whh0, bih0, bhh0, Wih1, Whh1, bih1, bhh1, Wlin, blin, out);
}

// Round 12
// 6550.935 us; speedup vs baseline: 1.0436x; 1.0259x over previous
//
#include <hip/hip_runtime.h>

#define BB 256
#define TT 2048
#define HH 128
#define HP 136     // padded h1-row stride (f16) to break phase-B bank conflicts
#define G4 512
#define INW 4
#define OUTW 4
#define TC 56      // time-chunk (2048 = 36*56 + 32, both even)
#define NT 512

typedef _Float16 f16x8 __attribute__((ext_vector_type(8)));
typedef float    f32x4 __attribute__((ext_vector_type(4)));

#define MFMA(A,B,C) __builtin_amdgcn_mfma_f32_16x16x32_f16((A),(B),(C),0,0,0)

__device__ __forceinline__ float sigm(float x)  { return __fdividef(1.f, 1.f + __expf(-x)); }
__device__ __forceinline__ float tanh_(float x) { return __fdividef(2.f, 1.f + __expf(-2.f*x)) - 1.f; }

// R11 post-mortem: frags spilled at the 64-VGPR budget (WRITE_SIZE 102MB =
// scratch stores), and the shfl-chain cell update wasted issue. Redesign:
//   C-rows = (unit,gate): A = W-tile with wrow = gate*128 + unit for tile-row
//   r_g = tile*16 + r, (unit = r_g>>2, gate = r_g&3); B = h broadcast into all
//   16 cols (same addr for every lane -> LDS broadcast, no mask). Every lane
//   then holds one unit's 4 gates in acc[0..3] -> cell update is LANE-LOCAL
//   (no shfl, no divergence); h-writes gated to r==0 lanes.
// NT=512: 8 waves x 4 tiles; frags 16 x f16x8 = 64 VGPR (budget 128, no spill).
// acc-init = buf[t][r_g] (f32x4 broadcast) folds xg0/xg1+bias before the MFMAs.
// Phase B reuses the same frag registers (A/B per-lane layouts coincide).

#define LDF(dst, wrj, kk) do {                                                 \
    const float* p_ = Mp_ + (size_t)(wrj) * HH + (kk)*32 + (kq << 3);          \
    const float4 lo_ = *(const float4*)p_;                                     \
    const float4 hi_ = *(const float4*)(p_ + 4);                               \
    dst = (f16x8){(_Float16)lo_.x,(_Float16)lo_.y,(_Float16)lo_.z,             \
                  (_Float16)lo_.w,(_Float16)hi_.x,(_Float16)hi_.y,             \
                  (_Float16)hi_.z,(_Float16)hi_.w}; } while (0)

#define LOADW(M) do { const float* Mp_ = (M);                                  \
    LDF(w00, wr0,      0); LDF(w01, wr0,      1); LDF(w02, wr0,      2); LDF(w03, wr0,      3); \
    LDF(w10, wr0 + 4,  0); LDF(w11, wr0 + 4,  1); LDF(w12, wr0 + 4,  2); LDF(w13, wr0 + 4,  3); \
    LDF(w20, wr0 + 8,  0); LDF(w21, wr0 + 8,  1); LDF(w22, wr0 + 8,  2); LDF(w23, wr0 + 8,  3); \
    LDF(w30, wr0 + 12, 0); LDF(w31, wr0 + 12, 1); LDF(w32, wr0 + 12, 2); LDF(w33, wr0 + 12, 3); \
} while (0)

// one recurrence GEMV: 4 kappa-blocks, B = h broadcast (addr indep. of lane r)
#define RSTEP(HB) do {                                                         \
    f16x8 hv_;                                                                 \
    hv_ = *(const f16x8*)((HB) + (kq << 3));                                   \
    a0 = MFMA(w00, hv_, a0); a1 = MFMA(w10, hv_, a1);                          \
    a2 = MFMA(w20, hv_, a2); a3 = MFMA(w30, hv_, a3);                          \
    hv_ = *(const f16x8*)((HB) + 32 + (kq << 3));                              \
    a0 = MFMA(w01, hv_, a0); a1 = MFMA(w11, hv_, a1);                          \
    a2 = MFMA(w21, hv_, a2); a3 = MFMA(w31, hv_, a3);                          \
    hv_ = *(const f16x8*)((HB) + 64 + (kq << 3));                              \
    a0 = MFMA(w02, hv_, a0); a1 = MFMA(w12, hv_, a1);                          \
    a2 = MFMA(w22, hv_, a2); a3 = MFMA(w32, hv_, a3);                          \
    hv_ = *(const f16x8*)((HB) + 96 + (kq << 3));                              \
    a0 = MFMA(w03, hv_, a0); a1 = MFMA(w13, hv_, a1);                          \
    a2 = MFMA(w23, hv_, a2); a3 = MFMA(w33, hv_, a3); } while (0)

#define UPD(AJ, CJ, HN) do {                                                   \
    const float i_ = sigm(AJ[0]);                                              \
    const float f_ = sigm(AJ[1]);                                              \
    const float g_ = tanh_(AJ[2]);                                             \
    const float o_ = sigm(AJ[3]);                                              \
    CJ = f_ * CJ + i_ * g_;                                                    \
    HN = o_ * tanh_(CJ); } while (0)

extern "C" __global__ void
__attribute__((amdgpu_flat_work_group_size(NT, NT)))
lstm2_fused(const float* __restrict__ x,
            const float* __restrict__ Wih0, const float* __restrict__ Whh0,
            const float* __restrict__ bih0, const float* __restrict__ bhh0,
            const float* __restrict__ Wih1, const float* __restrict__ Whh1,
            const float* __restrict__ bih1, const float* __restrict__ bhh1,
            const float* __restrict__ Wlin, const float* __restrict__ blin,
            float* __restrict__ out)
{
    // static LDS ~140 KB
    __shared__ __align__(16) _Float16 h1h[(TC + 9) * HP]; // h1 ring (padded rows)
    __shared__ __align__(16) float    buf[TC * G4];       // xg0, then xg1 (fp32)
    __shared__ __align__(16) _Float16 h2h[2 * HH];        // h2 dbuf, parity t&1
    __shared__ float xc[TC * INW];
    __shared__ float b0c[G4], b1c[G4];                    // biases, W-row indexed
    __shared__ float wlc[OUTW * HH];
    __shared__ float blc[OUTW];

    const int i    = threadIdx.x;
    const int w    = i >> 6;            // wave 0..7 -> tiles 4w..4w+3
    const int lane = i & 63;
    const int r    = lane & 15;         // A-row / B-col within tile
    const int kq   = lane >> 4;         // k-quarter
    const bool c0  = (r == 0);          // owner lanes for cell update writes
    const int b    = blockIdx.x;

    // wrow for tile j at A-row r:  (r&3)*128 + (4w+j)*4 + (r>>2)
    const int wr0 = ((r & 3) << 7) | (r >> 2) | (w << 4);

    if (i < G4) { b0c[i] = bih0[i] + bhh0[i]; b1c[i] = bih1[i] + bhh1[i]; }
    wlc[i] = Wlin[i];                   // NT == OUTW*HH == 512
    if (i < OUTW) blc[i] = blin[i];
    if (i < HH) { h1h[i] = (_Float16)0.f; h2h[i] = (_Float16)0.f; }

    float c10 = 0.f, c11 = 0.f, c12 = 0.f, c13 = 0.f;   // layer-0 cells
    float c20 = 0.f, c21 = 0.f, c22 = 0.f, c23 = 0.f;   // layer-1 cells
    f16x8 w00, w01, w02, w03, w10, w11, w12, w13,
          w20, w21, w22, w23, w30, w31, w32, w33;

    const float* xb   = x   + (size_t)b * TT * INW;
    float*       vout = out + (size_t)b * TT * OUTW;
    float*       zout = out + (size_t)BB * TT * OUTW + (size_t)b * HH;

    for (int t0 = 0; t0 < TT; t0 += TC) {
        const int tc = (TT - t0 < TC) ? (TT - t0) : TC;

        if (t0 > 0 && i < HH) h1h[i] = h1h[TC * HP + i];   // carry ring
        for (int j = i; j < tc * INW; j += NT) xc[j] = xb[t0 * INW + j];
        __syncthreads();

        // xg0 bulk: buf[t][rg] = b0 + Wih0[row] . x_t   (rg = unit*4+gate)
        for (int idx = i; idx < tc * G4; idx += NT) {
            const int t = idx >> 9, rg = idx & 511;
            const int row = ((rg & 3) << 7) | (rg >> 2);
            const float4 wv = *(const float4*)(Wih0 + (size_t)row * INW);
            const float4 xv = *(const float4*)(xc + t * INW);
            buf[idx] = b0c[row] + wv.x*xv.x + wv.y*xv.y + wv.z*xv.z + wv.w*xv.w;
        }
        LOADW(Whh0);
        __syncthreads();

        // ================= Phase A: layer-0 recurrence =================
        for (int t = 0; t < tc; ++t) {
            const float* bp = buf + t * G4 + (w << 6) + (kq << 2);
            f32x4 a0 = *(const f32x4*)(bp);
            f32x4 a1 = *(const f32x4*)(bp + 16);
            f32x4 a2 = *(const f32x4*)(bp + 32);
            f32x4 a3 = *(const f32x4*)(bp + 48);
            RSTEP(h1h + t * HP);
            float hn0, hn1, hn2, hn3;
            UPD(a0, c10, hn0); UPD(a1, c11, hn1);
            UPD(a2, c12, hn2); UPD(a3, c13, hn3);
            if (c0) {                    // unit = 16w + 4j + kq
                _Float16* hw = h1h + (t + 1) * HP + (w << 4) + kq;
                hw[0] = (_Float16)hn0; hw[4]  = (_Float16)hn1;
                hw[8] = (_Float16)hn2; hw[12] = (_Float16)hn3;
            }
            __syncthreads();
        }

        // ===== Phase B: xg1 = Wih1 @ h1 + b1 (bulk, A = h1 time-rows) =====
        LOADW(Wih1);
        const int ntb = (tc + 15) >> 4;
        for (int tb = 0; tb < ntb; ++tb) {
            f32x4 a0 = {0.f,0.f,0.f,0.f}, a1 = {0.f,0.f,0.f,0.f},
                  a2 = {0.f,0.f,0.f,0.f}, a3 = {0.f,0.f,0.f,0.f};
            const _Float16* ha = h1h + (tb * 16 + r + 1) * HP;
            f16x8 tv;
            tv = *(const f16x8*)(ha + (kq << 3));
            a0 = MFMA(tv, w00, a0); a1 = MFMA(tv, w10, a1);
            a2 = MFMA(tv, w20, a2); a3 = MFMA(tv, w30, a3);
            tv = *(const f16x8*)(ha + 32 + (kq << 3));
            a0 = MFMA(tv, w01, a0); a1 = MFMA(tv, w11, a1);
            a2 = MFMA(tv, w21, a2); a3 = MFMA(tv, w31, a3);
            tv = *(const f16x8*)(ha + 64 + (kq << 3));
            a0 = MFMA(tv, w02, a0); a1 = MFMA(tv, w12, a1);
            a2 = MFMA(tv, w22, a2); a3 = MFMA(tv, w32, a3);
            tv = *(const f16x8*)(ha + 96 + (kq << 3));
            a0 = MFMA(tv, w03, a0); a1 = MFMA(tv, w13, a1);
            a2 = MFMA(tv, w23, a2); a3 = MFMA(tv, w33, a3);
            const float b_0 = b1c[wr0],     b_1 = b1c[wr0 + 4];
            const float b_2 = b1c[wr0 + 8], b_3 = b1c[wr0 + 12];
            #pragma unroll
            for (int e = 0; e < 4; ++e) {       // C row = local time
                const int tl = tb * 16 + (kq << 2) + e;
                if (tl < tc) {
                    float* bq = buf + tl * G4 + (w << 6) + r;
                    bq[0]  = a0[e] + b_0;
                    bq[16] = a1[e] + b_1;
                    bq[32] = a2[e] + b_2;
                    bq[48] = a3[e] + b_3;
                }
            }
        }
        __syncthreads();

        // ====== Phase C: layer-1 recurrence + projection + z ==========
        LOADW(Whh1);
        for (int t = 0; t < tc; ++t) {
            const int rb = (t & 1) * HH, wbuf = rb ^ HH;
            const float* bp = buf + t * G4 + (w << 6) + (kq << 2);
            f32x4 a0 = *(const f32x4*)(bp);
            f32x4 a1 = *(const f32x4*)(bp + 16);
            f32x4 a2 = *(const f32x4*)(bp + 32);
            f32x4 a3 = *(const f32x4*)(bp + 48);
            RSTEP(h2h + rb);
            float hn0, hn1, hn2, hn3;
            UPD(a0, c20, hn0); UPD(a1, c21, hn1);
            UPD(a2, c22, hn2); UPD(a3, c23, hn3);
            if (c0) {
                _Float16* hw = h2h + wbuf + (w << 4) + kq;
                hw[0] = (_Float16)hn0; hw[4]  = (_Float16)hn1;
                hw[8] = (_Float16)hn2; hw[12] = (_Float16)hn3;
                if (t0 + t == TT - 1) {
                    const int u = (w << 4) + kq;
                    zout[u] = hn0; zout[u + 4]  = hn1;
                    zout[u + 8] = hn2; zout[u + 12] = hn3;
                }
            }
            __syncthreads();
            if (i < 256) {              // v[b,t,:] from fresh h2
                const int o = i >> 6, l = i & 63;
                float p2 = (float)h2h[wbuf + l]      * wlc[o*HH + l]
                         + (float)h2h[wbuf + 64 + l] * wlc[o*HH + 64 + l];
                p2 += __shfl_xor(p2, 32);
                p2 += __shfl_xor(p2, 16);
                p2 += __shfl_xor(p2, 8);
                p2 += __shfl_xor(p2, 4);
                p2 += __shfl_xor(p2, 2);
                p2 += __shfl_xor(p2, 1);
                if (l == 0) vout[(size_t)(t0 + t) * OUTW + o] = p2 + blc[o];
            }
        }
    }
}

extern "C" void kernel_launch(void* const* d_in, const int* in_sizes, int n_in,
                              void* d_out, int out_size, void* d_ws, size_t ws_size,
                              hipStream_t stream) {
    const float* x    = (const float*)d_in[0];
    const float* Wih0 = (const float*)d_in[1];
    const float* Whh0 = (const float*)d_in[2];
    const float* bih0 = (const float*)d_in[3];
    const float* bhh0 = (const float*)d_in[4];
    const float* Wih1 = (const float*)d_in[5];
    const float* Whh1 = (const float*)d_in[6];
    const float* bih1 = (const float*)d_in[7];
    const float* bhh1 = (const float*)d_in[8];
    const float* Wlin = (const float*)d_in[9];
    const float* blin = (const float*)d_in[10];
    float* out = (float*)d_out;

    lstm2_fused<<<dim3(BB), dim3(NT), 0, stream>>>(
        x, Wih0, Whh0, bih0, bhh0, Wih1, Whh1, bih1, bhh1, Wlin, blin, out);
}

// Round 13
// 3048.486 us; speedup vs baseline: 2.2425x; 2.1489x over previous
//
#include <hip/hip_runtime.h>

#define BB 256
#define TT 2048
#define HH 128
#define HP 136     // padded h1-row stride (f16) to break phase-B bank conflicts
#define G4 512
#define INW 4
#define OUTW 4
#define TC 56      // time-chunk (2048 = 36*56 + 32, both even)
#define NT 512

typedef _Float16 f16x8 __attribute__((ext_vector_type(8)));
typedef float    f32x4 __attribute__((ext_vector_type(4)));

#define MFMA(A,B,C) __builtin_amdgcn_mfma_f32_16x16x32_f16((A),(B),(C),0,0,0)

__device__ __forceinline__ float sigm(float x)  { return __fdividef(1.f, 1.f + __expf(-x)); }
__device__ __forceinline__ float tanh_(float x) { return __fdividef(2.f, 1.f + __expf(-2.f*x)) - 1.f; }

// R12 post-mortem: no spill, but VALUBusy 78% — UPD ran on all 64 lanes for 4
// units each (16x col redundancy) = 40 trans-instr/wave/step at ~8cyc each.
// R13: each lane updates ONE unit (j = col&3), selected from its 4 acc vectors
// with 12 cndmask (static unroll); h-write gated to col<4. Trans 40 -> 10
// instr/wave/step; cell state 4 -> 1 float per lane per layer. Identical math.
//
// Layout (verified passing R11/R12):
//   A-frag: W-tile, wrow_j = ((r&3)<<7) | (w<<4) | (j<<2) | (r>>2)
//     -> C-row r of tile j: gate = r&3, unit = w*16 + j*4 + r>>2
//   B-frag: h broadcast to all 16 cols (wave-uniform LDS read)
//   C: lane l holds rows kq*4+e (e = gate), col = l&15 (replicated)
//   -> lane's acc[j][e] = gate e of unit w*16 + j*4 + kq

#define LDF(dst, wrj, kk) do {                                                 \
    const float* p_ = Mp_ + (size_t)(wrj) * HH + (kk)*32 + (kq << 3);          \
    const float4 lo_ = *(const float4*)p_;                                     \
    const float4 hi_ = *(const float4*)(p_ + 4);                               \
    dst = (f16x8){(_Float16)lo_.x,(_Float16)lo_.y,(_Float16)lo_.z,             \
                  (_Float16)lo_.w,(_Float16)hi_.x,(_Float16)hi_.y,             \
                  (_Float16)hi_.z,(_Float16)hi_.w}; } while (0)

#define LOADW(M) do { const float* Mp_ = (M);                                  \
    LDF(w00, wr0,      0); LDF(w01, wr0,      1); LDF(w02, wr0,      2); LDF(w03, wr0,      3); \
    LDF(w10, wr0 + 4,  0); LDF(w11, wr0 + 4,  1); LDF(w12, wr0 + 4,  2); LDF(w13, wr0 + 4,  3); \
    LDF(w20, wr0 + 8,  0); LDF(w21, wr0 + 8,  1); LDF(w22, wr0 + 8,  2); LDF(w23, wr0 + 8,  3); \
    LDF(w30, wr0 + 12, 0); LDF(w31, wr0 + 12, 1); LDF(w32, wr0 + 12, 2); LDF(w33, wr0 + 12, 3); \
} while (0)

// one recurrence GEMV: 4 k-blocks, B = h broadcast (addr indep. of lane)
#define RSTEP(HB) do {                                                         \
    f16x8 hv_;                                                                 \
    hv_ = *(const f16x8*)((HB) + (kq << 3));                                   \
    a0 = MFMA(w00, hv_, a0); a1 = MFMA(w10, hv_, a1);                          \
    a2 = MFMA(w20, hv_, a2); a3 = MFMA(w30, hv_, a3);                          \
    hv_ = *(const f16x8*)((HB) + 32 + (kq << 3));                              \
    a0 = MFMA(w01, hv_, a0); a1 = MFMA(w11, hv_, a1);                          \
    a2 = MFMA(w21, hv_, a2); a3 = MFMA(w31, hv_, a3);                          \
    hv_ = *(const f16x8*)((HB) + 64 + (kq << 3));                              \
    a0 = MFMA(w02, hv_, a0); a1 = MFMA(w12, hv_, a1);                          \
    a2 = MFMA(w22, hv_, a2); a3 = MFMA(w32, hv_, a3);                          \
    hv_ = *(const f16x8*)((HB) + 96 + (kq << 3));                              \
    a0 = MFMA(w03, hv_, a0); a1 = MFMA(w13, hv_, a1);                          \
    a2 = MFMA(w23, hv_, a2); a3 = MFMA(w33, hv_, a3); } while (0)

// pick my tile's gate vector (j = col&3) with static-unrolled cndmask selects,
// then one lane-local LSTM update. All lanes execute (4x redundant), but the
// wave issues only ONE unit's transcendentals.
#define UPDSEL(CJ, HN) do {                                                    \
    f32x4 av_;                                                                 \
    _Pragma("unroll")                                                          \
    for (int e_ = 0; e_ < 4; ++e_) {                                           \
        const float t01_ = j1 ? a1[e_] : a0[e_];                               \
        const float t23_ = j1 ? a3[e_] : a2[e_];                               \
        av_[e_] = j2 ? t23_ : t01_;                                            \
    }                                                                          \
    const float i_ = sigm(av_[0]);                                             \
    const float f_ = sigm(av_[1]);                                             \
    const float g_ = tanh_(av_[2]);                                            \
    const float o_ = sigm(av_[3]);                                             \
    CJ = f_ * CJ + i_ * g_;                                                    \
    HN = o_ * tanh_(CJ); } while (0)

extern "C" __global__ void
__attribute__((amdgpu_flat_work_group_size(NT, NT)))
lstm2_fused(const float* __restrict__ x,
            const float* __restrict__ Wih0, const float* __restrict__ Whh0,
            const float* __restrict__ bih0, const float* __restrict__ bhh0,
            const float* __restrict__ Wih1, const float* __restrict__ Whh1,
            const float* __restrict__ bih1, const float* __restrict__ bhh1,
            const float* __restrict__ Wlin, const float* __restrict__ blin,
            float* __restrict__ out)
{
    // static LDS ~140 KB
    __shared__ __align__(16) _Float16 h1h[(TC + 9) * HP]; // h1 ring (padded rows)
    __shared__ __align__(16) float    buf[TC * G4];       // xg0, then xg1 (fp32)
    __shared__ __align__(16) _Float16 h2h[2 * HH];        // h2 dbuf, parity t&1
    __shared__ float xc[TC * INW];
    __shared__ float b0c[G4], b1c[G4];                    // biases, W-row indexed
    __shared__ float wlc[OUTW * HH];
    __shared__ float blc[OUTW];

    const int i    = threadIdx.x;
    const int w    = i >> 6;            // wave 0..7 -> tiles 4w..4w+3
    const int lane = i & 63;
    const int r    = lane & 15;         // A-row / B-col within tile
    const int kq   = lane >> 4;         // k-quarter
    const int b    = blockIdx.x;

    // wrow for tile j at A-row r:  (r&3)*128 + (4w+j)*4 + (r>>2)
    const int wr0 = ((r & 3) << 7) | (r >> 2) | (w << 4);

    // per-lane UPD assignment: tile j = col&3, unit = w*16 + j*4 + kq
    const bool j1 = (r & 1), j2 = (r & 2);
    const int  myu = (w << 4) | ((r & 3) << 2) | kq;   // my unit (valid for r<4)
    const bool own = (r < 4);                          // h-writer lanes

    if (i < G4) { b0c[i] = bih0[i] + bhh0[i]; b1c[i] = bih1[i] + bhh1[i]; }
    wlc[i] = Wlin[i];                   // NT == OUTW*HH == 512
    if (i < OUTW) blc[i] = blin[i];
    if (i < HH) { h1h[i] = (_Float16)0.f; h2h[i] = (_Float16)0.f; }

    float c1 = 0.f, c2 = 0.f;           // my unit's cell state (per layer)
    f16x8 w00, w01, w02, w03, w10, w11, w12, w13,
          w20, w21, w22, w23, w30, w31, w32, w33;

    const float* xb   = x   + (size_t)b * TT * INW;
    float*       vout = out + (size_t)b * TT * OUTW;
    float*       zout = out + (size_t)BB * TT * OUTW + (size_t)b * HH;

    for (int t0 = 0; t0 < TT; t0 += TC) {
        const int tc = (TT - t0 < TC) ? (TT - t0) : TC;

        if (t0 > 0 && i < HH) h1h[i] = h1h[TC * HP + i];   // carry ring
        for (int j = i; j < tc * INW; j += NT) xc[j] = xb[t0 * INW + j];
        __syncthreads();

        // xg0 bulk: buf[t][rg] = b0 + Wih0[row] . x_t   (rg = unit*4+gate)
        for (int idx = i; idx < tc * G4; idx += NT) {
            const int t = idx >> 9, rg = idx & 511;
            const int row = ((rg & 3) << 7) | (rg >> 2);
            const float4 wv = *(const float4*)(Wih0 + (size_t)row * INW);
            const float4 xv = *(const float4*)(xc + t * INW);
            buf[idx] = b0c[row] + wv.x*xv.x + wv.y*xv.y + wv.z*xv.z + wv.w*xv.w;
        }
        LOADW(Whh0);
        __syncthreads();

        // ================= Phase A: layer-0 recurrence =================
        for (int t = 0; t < tc; ++t) {
            const float* bp = buf + t * G4 + (w << 6) + (kq << 2);
            f32x4 a0 = *(const f32x4*)(bp);
            f32x4 a1 = *(const f32x4*)(bp + 16);
            f32x4 a2 = *(const f32x4*)(bp + 32);
            f32x4 a3 = *(const f32x4*)(bp + 48);
            RSTEP(h1h + t * HP);
            float hn;
            UPDSEL(c1, hn);
            if (own) h1h[(t + 1) * HP + myu] = (_Float16)hn;
            __syncthreads();
        }

        // ===== Phase B: xg1 = Wih1 @ h1 + b1 (bulk, A = h1 time-rows) =====
        LOADW(Wih1);
        const int ntb = (tc + 15) >> 4;
        for (int tb = 0; tb < ntb; ++tb) {
            f32x4 a0 = {0.f,0.f,0.f,0.f}, a1 = {0.f,0.f,0.f,0.f},
                  a2 = {0.f,0.f,0.f,0.f}, a3 = {0.f,0.f,0.f,0.f};
            const _Float16* ha = h1h + (tb * 16 + r + 1) * HP;
            f16x8 tv;
            tv = *(const f16x8*)(ha + (kq << 3));
            a0 = MFMA(tv, w00, a0); a1 = MFMA(tv, w10, a1);
            a2 = MFMA(tv, w20, a2); a3 = MFMA(tv, w30, a3);
            tv = *(const f16x8*)(ha + 32 + (kq << 3));
            a0 = MFMA(tv, w01, a0); a1 = MFMA(tv, w11, a1);
            a2 = MFMA(tv, w21, a2); a3 = MFMA(tv, w31, a3);
            tv = *(const f16x8*)(ha + 64 + (kq << 3));
            a0 = MFMA(tv, w02, a0); a1 = MFMA(tv, w12, a1);
            a2 = MFMA(tv, w22, a2); a3 = MFMA(tv, w32, a3);
            tv = *(const f16x8*)(ha + 96 + (kq << 3));
            a0 = MFMA(tv, w03, a0); a1 = MFMA(tv, w13, a1);
            a2 = MFMA(tv, w23, a2); a3 = MFMA(tv, w33, a3);
            const float b_0 = b1c[wr0],     b_1 = b1c[wr0 + 4];
            const float b_2 = b1c[wr0 + 8], b_3 = b1c[wr0 + 12];
            #pragma unroll
            for (int e = 0; e < 4; ++e) {       // C row = local time
                const int tl = tb * 16 + (kq << 2) + e;
                if (tl < tc) {
                    float* bq = buf + tl * G4 + (w << 6) + r;
                    bq[0]  = a0[e] + b_0;
                    bq[16] = a1[e] + b_1;
                    bq[32] = a2[e] + b_2;
                    bq[48] = a3[e] + b_3;
                }
            }
        }
        __syncthreads();

        // ====== Phase C: layer-1 recurrence + projection + z ==========
        LOADW(Whh1);
        for (int t = 0; t < tc; ++t) {
            const int rb = (t & 1) * HH, wbuf = rb ^ HH;
            const float* bp = buf + t * G4 + (w << 6) + (kq << 2);
            f32x4 a0 = *(const f32x4*)(bp);
            f32x4 a1 = *(const f32x4*)(bp + 16);
            f32x4 a2 = *(const f32x4*)(bp + 32);
            f32x4 a3 = *(const f32x4*)(bp + 48);
            RSTEP(h2h + rb);
            float hn;
            UPDSEL(c2, hn);
            if (own) {
                h2h[wbuf + myu] = (_Float16)hn;
                if (t0 + t == TT - 1) zout[myu] = hn;
            }
            __syncthreads();
            if (i < 256) {              // v[b,t,:] from fresh h2
                const int o = i >> 6, l = i & 63;
                float p2 = (float)h2h[wbuf + l]      * wlc[o*HH + l]
                         + (float)h2h[wbuf + 64 + l] * wlc[o*HH + 64 + l];
                p2 += __shfl_xor(p2, 32);
                p2 += __shfl_xor(p2, 16);
                p2 += __shfl_xor(p2, 8);
                p2 += __shfl_xor(p2, 4);
                p2 += __shfl_xor(p2, 2);
                p2 += __shfl_xor(p2, 1);
                if (l == 0) vout[(size_t)(t0 + t) * OUTW + o] = p2 + blc[o];
            }
        }
    }
}

extern "C" void kernel_launch(void* const* d_in, const int* in_sizes, int n_in,
                              void* d_out, int out_size, void* d_ws, size_t ws_size,
                              hipStream_t stream) {
    const float* x    = (const float*)d_in[0];
    const float* Wih0 = (const float*)d_in[1];
    const float* Whh0 = (const float*)d_in[2];
    const float* bih0 = (const float*)d_in[3];
    const float* bhh0 = (const float*)d_in[4];
    const float* Wih1 = (const float*)d_in[5];
    const float* Whh1 = (const float*)d_in[6];
    const float* bih1 = (const float*)d_in[7];
    const float* bhh1 = (const float*)d_in[8];
    const float* Wlin = (const float*)d_in[9];
    const float* blin = (const float*)d_in[10];
    float* out = (float*)d_out;

    lstm2_fused<<<dim3(BB), dim3(NT), 0, stream>>>(
        x, Wih0, Whh0, bih0, bhh0, Wih1, Whh1, bih1, bhh1, Wlin, blin, out);
}